// Round 4
// baseline (691.782 us; speedup 1.0000x reference)
//
#include <hip/hip_runtime.h>
#include <hip/hip_bf16.h>
#include <stdint.h>

// ---- problem constants ----
#define NB   65536      // batch points
#define NC   2
#define NV   3
#define ND   64
#define NK   1024       // codebook entries
#define NS   4
#define NH   1024
#define NL   5
#define NF   25
#define NIN  102
#define K0P  128        // padded layer-0 K

typedef float f32x4 __attribute__((ext_vector_type(4)));
typedef int   i32x4 __attribute__((ext_vector_type(4)));
typedef int   i32x8 __attribute__((ext_vector_type(8)));
typedef unsigned char u8;

__device__ __forceinline__ void load_lds16(const void* g, void* l) {
    __builtin_amdgcn_global_load_lds(
        (const __attribute__((address_space(1))) void*)g,
        (__attribute__((address_space(3))) void*)l,
        16, 0, 0);
}

// fp8 e4m3 scalar convert (RNE, saturating): low byte of cvt_pk
__device__ __forceinline__ u8 to_fp8(float x) {
    return (u8)(__builtin_amdgcn_cvt_pk_fp8_f32(x, 0.0f, 0, false) & 0xff);
}

__device__ __forceinline__ f32x4 mfma128(i32x8 wf, i32x8 af, f32x4 c) {
    // swapped operands: D rows (q*4+r) = n-dim, cols (r16) = m-dim
    return __builtin_amdgcn_mfma_scale_f32_16x16x128_f8f6f4(
        wf, af, c, 0, 0,
        0, 0x79797979,    // scale src0 (W): 2^-6
        0, 0x7f7f7f7f);   // scale src1 (A): 2^0
}

// ===========================================================================
// TILED OPERAND LAYOUTS
//  W_t: flat = (((bn*nIt + it)*8 + j)*2 + half)*1024 + (q*16+r16)*16 + b16
//       holds W[n][k]: n = bn*128 + j*16 + r16, k = it*128 + q*32 + half*16 + b16.
//       Per-(bn,it) slab = 16 KB contiguous -> global_load_lds staging;
//       frag ds_read = 2x b128 at stride-16 (conflict-free).
//  A_t: flat = ((m16*(K/32) + c32)*16 + r)*32 + b
//       holds A[m][k]: m = m16*16 + r, k = c32*32 + b. 512B-chunk contiguous.
// ===========================================================================

// ---------------------------------------------------------------------------
// VQ kernel: single block, 1024 threads (one codebook row per thread). fp32.
// ---------------------------------------------------------------------------
__global__ __launch_bounds__(1024) void vq_kernel(
    const float* __restrict__ latents, const int* __restrict__ latent_idx,
    const float* __restrict__ codebooks, float* __restrict__ zq_out,
    float* __restrict__ out) {
    __shared__ float zcur[ND], resid[ND], zqsum[ND], ssq[ND];
    __shared__ float sDw[16];
    __shared__ int   sKw[16];
    __shared__ int   sBest;
    int t = threadIdx.x, lane = t & 63, wv = t >> 6;
    const float* img = latents + (size_t)latent_idx[0] * (NS * ND);
    if (t < ND) { resid[t] = 0.f; zqsum[t] = 0.f; }
    __syncthreads();
    float lossAcc = 0.f;   // thread 0 only
    for (int s = 0; s < NS; s++) {
        if (t < ND) {
            float iv = img[s * ND + t];
            float r  = resid[t] + iv;
            resid[t] = r;
            zcur[t]  = (s == 0) ? iv : (r - zqsum[t]);
        }
        __syncthreads();
        float zz = 0.f;
#pragma unroll
        for (int d = 0; d < ND; d++) { float z = zcur[d]; zz += z * z; }
        const float4* e4 = (const float4*)(codebooks + ((size_t)s * NK + t) * ND);
        float dot = 0.f, ee = 0.f;
#pragma unroll
        for (int i = 0; i < 16; i++) {
            float4 v = e4[i];
            dot += zcur[4 * i + 0] * v.x; dot += zcur[4 * i + 1] * v.y;
            dot += zcur[4 * i + 2] * v.z; dot += zcur[4 * i + 3] * v.w;
            ee  += v.x * v.x; ee += v.y * v.y; ee += v.z * v.z; ee += v.w * v.w;
        }
        float dmin = zz - 2.0f * dot + ee;
        int   kmin = t;
#pragma unroll
        for (int m = 1; m < 64; m <<= 1) {
            float d2 = __shfl_xor(dmin, m);
            int   k2 = __shfl_xor(kmin, m);
            if (d2 < dmin || (d2 == dmin && k2 < kmin)) { dmin = d2; kmin = k2; }
        }
        if (lane == 0) { sDw[wv] = dmin; sKw[wv] = kmin; }
        __syncthreads();
        if (t == 0) {
            float bd = sDw[0]; int bk = sKw[0];
            for (int w = 1; w < 16; w++) {
                float d2 = sDw[w]; int k2 = sKw[w];
                if (d2 < bd || (d2 == bd && k2 < bk)) { bd = d2; bk = k2; }
            }
            sBest = bk;
            out[NB * NV + s] = (float)bk;
        }
        __syncthreads();
        int best = sBest;
        const float* eb = codebooks + ((size_t)s * NK + best) * ND;
        if (t < ND) {
            float zq = eb[t];
            float d  = zq - zcur[t];
            ssq[t]   = d * d;
            zqsum[t] = zqsum[t] + (zq + (zcur[t] - zq));   // z_q_st forward (exact ref arith)
        }
        __syncthreads();
        if (t == 0) {
            float sum = 0.f;
            for (int d = 0; d < ND; d++) sum += ssq[d];
            lossAcc += 0.25f * (sum / (float)ND);
        }
    }
    if (t < ND) zq_out[t] = zqsum[t];
    if (t == 0) out[NB * NV + NS] = lossAcc;
}

// ---------------------------------------------------------------------------
// betas fused with decoder biases (fp32)
// ---------------------------------------------------------------------------
__global__ __launch_bounds__(256) void betas_kernel(
    const float* __restrict__ zq, const float* __restrict__ mod_W,
    const float* __restrict__ mod_b, const float* __restrict__ b0,
    const float* __restrict__ bh, float* __restrict__ bb) {
    int g = blockIdx.x * 256 + threadIdx.x;   // < 5120
    int l = g >> 10, n = g & 1023;
    float acc = mod_b[g];
    for (int d = 0; d < ND; d++) acc += zq[d] * mod_W[(size_t)(l * ND + d) * NH + n];
    acc += (l == 0) ? b0[n] : bh[(size_t)(l - 1) * NH + n];
    bb[g] = acc;
}

// ---------------------------------------------------------------------------
// out init: values[m][v] = bout[v] (atomic-add target for the fused layer)
// ---------------------------------------------------------------------------
__global__ __launch_bounds__(256) void init_out_kernel(
    const float* __restrict__ bout, float* __restrict__ out) {
    int g = blockIdx.x * 256 + threadIdx.x;   // < NB*NV
    out[g] = bout[g % NV];
}

// ---------------------------------------------------------------------------
// Weight prep: fp32 [Ks][1024] -> fp8 e4m3 W_t tiled (x64, undone by the
// MFMA e8m0 scale 2^-6). Zero-pad k>=Ks. nIt = Kp/128. Half-split layout.
// ---------------------------------------------------------------------------
__global__ __launch_bounds__(256) void prep_kernel(
    const float* __restrict__ src, u8* __restrict__ dst, int Ks, int Kp) {
    __shared__ float tile[32][33];
    int nIt = Kp >> 7;
    src += (size_t)blockIdx.z * Ks * NH;
    dst += (size_t)blockIdx.z * NH * Kp;
    int k0 = blockIdx.x * 32, n0 = blockIdx.y * 32;
    int tx = threadIdx.x, ty = threadIdx.y;   // (32, 8)
    for (int i = 0; i < 4; i++) {
        int k = k0 + ty + i * 8;
        int n = n0 + tx;
        tile[ty + i * 8][tx] = (k < Ks) ? src[(size_t)k * NH + n] : 0.0f;
    }
    __syncthreads();
    for (int i = 0; i < 4; i++) {
        int n = n0 + ty + i * 8;
        int k = k0 + tx;
        int bn = n >> 7, j = (n >> 4) & 7, r16 = n & 15;
        int it = k >> 7, q = (k >> 5) & 3, half = (k >> 4) & 1, b16 = k & 15;
        size_t flat = ((size_t)(((bn * nIt + it) * 8 + j) * 2 + half)) * 1024
                    + (q * 16 + r16) * 16 + b16;
        dst[flat] = to_fp8(tile[tx][ty + i * 8] * 64.0f);
    }
}

// ---------------------------------------------------------------------------
// Positional encoding -> fp8 A_t tiled [Bc][128] (K/32 = 4 chunks)
// ---------------------------------------------------------------------------
__device__ __forceinline__ float pe_val(const float* coords, int m, int k) {
    if (k < 2) return coords[m * 2 + k];
    if (k >= NIN) return 0.0f;
    int u = k - 2;
    int f = u >> 2, r = u & 3;
    float c = coords[m * 2 + (r & 1)];
    float a = c * __builtin_ldexpf(3.14159274101257324f, f);
    return (r < 2) ? sinf(a) : cosf(a);
}

__global__ __launch_bounds__(256) void pe_kernel(
    const float* __restrict__ coords, u8* __restrict__ pe) {
    int g = blockIdx.x * 256 + threadIdx.x;   // < Bc*32
    int m = g >> 5, k4 = (g & 31) * 4;
    float v0 = pe_val(coords, m, k4 + 0);
    float v1 = pe_val(coords, m, k4 + 1);
    float v2 = pe_val(coords, m, k4 + 2);
    float v3 = pe_val(coords, m, k4 + 3);
    int p = __builtin_amdgcn_cvt_pk_fp8_f32(v0, v1, 0, false);
    p     = __builtin_amdgcn_cvt_pk_fp8_f32(v2, v3, p, true);
    // A_t (K=128): flat = ((m16*4 + c32)*16 + r)*32 + b
    int m16 = m >> 4, r = m & 15, c32 = k4 >> 5, b = k4 & 31;
    *(int*)(pe + ((size_t)(m16 * 4 + c32) * 16 + r) * 32 + b) = p;
}

// ---------------------------------------------------------------------------
// MX-fp8 MFMA GEMM, R16: 8-WAVE (512-thread) 2-fat-phase schedule.
// R12 (2-barrier dbuf) and R15 (4-wave 8-phase counted) both pinned at
// MfmaUtil ~30% -- matching learn_hip m232: 4-wave phase-split is null
// because each SIMD holds 1 wave/block (cross-block waves are barrier-
// decoupled -> convoys). The verified wins (m196->m198->m201) all use
// 512-thread 8-wave blocks: 2 barrier-coupled waves per SIMD at micro-
// skewed phases. R16 ports that:
//   - block 256m x 128n, 8 waves as 2M x 4N, wave tile 128m x 32n,
//     acc[8][2] = 64 AGPR. Grid (Bc/256)*8, XCD-swizzled.
//   - BOTH A and W staged in LDS (A: 32 KB chunk-major; W: 16 KB slab),
//     TRIPLE-buffered (3 x 48 KB = 144 KB dynamic LDS, 1 block/CU).
//     A per-wave register double-buffer eliminated entirely.
//   - per K-iter (BK=128): 2 fat phases:
//       P0 {2 W-frag pairs + A-frags 0..3 (12 ds_read_b128) || 3 gload_lds
//           -> barrier -> setprio(1) -> 8 MFMA -> setprio(0) -> barrier}
//       P1 {A-frags 4..7 (8 ds) || 3 gload_lds -> barrier -> 8 MFMA
//           -> vmcnt(6) -> barrier}
//   - counted vmcnt(6) once per iter keeps the 6 stage-ops of tile(it+2)
//     in flight across the barrier (never 0 in the main loop, T4).
//     All loop VMEM ops are gload_lds -> vmcnt arithmetic is exact.
//   - LDS demand 160 KB/iter vs 2212-cy MFMA floor = 74 B/cy < 85 ceiling.
// MODE 0: relu(acc+bb) -> fp8, repack to next layer's A_t via LDS, coalesced.
// MODE 1: out[m][v] += relu(acc+bb).Wout[n][v], q-shfl + LDS wn-reduce +
//         one atomicAdd per (m, v) per block.
// ---------------------------------------------------------------------------
template <int MODE, int KT>
__global__ __launch_bounds__(512, 2) void gemm_kernel(
    const u8* __restrict__ A, const u8* __restrict__ W,
    const float* __restrict__ bb, u8* __restrict__ O,
    const float* __restrict__ Wout, float* __restrict__ out, int Mb) {
    extern __shared__ __align__(16) u8 smem[];   // 3 x 49152
    int t   = threadIdx.x;
    int fid = blockIdx.x;
    int xcd = fid & 7;
    int j8  = fid >> 3;                 // 0..Mb-1
    int bn  = j8 & 7;                   // fastest within an XCD
    int bm  = xcd * (Mb >> 3) + (j8 >> 3);   // 256-row m-tile index
    int lane = t & 63, w = t >> 6;      // 8 waves
    int wm2  = w >> 2, wn = w & 3;      // 2 m-rows x 4 n-cols
    int q    = lane >> 4, r16 = lane & 15;
    constexpr int nIt = KT >> 7;
    constexpr int KC  = KT >> 5;        // K/32 chunks per m16 row-group

    const u8* wslab = W + (size_t)(bn * nIt) * 16384;

    f32x4 acc[8][2];
    f32x4 zero = {0.f, 0.f, 0.f, 0.f};
    for (int i = 0; i < 8; i++) { acc[i][0] = zero; acc[i][1] = zero; }

#define FENCE asm volatile("" ::: "memory")

    // stage A chunk-pair call CC (0..3) of K-tile IT into buffer B:
    // covers LDS chunks w*8+CC*2 .. +1, per-lane global source.
#define STAGE_A(B, IT, CC)                                                     \
    {                                                                          \
        int lc = w * 8 + (CC) * 2 + (lane >> 5);                               \
        load_lds16((const void*)(A + ((size_t)(bm * 16 + (lc >> 2)) * KC       \
                                      + (IT) * 4 + (lc & 3)) * 512             \
                                 + (lane & 31) * 16),                          \
                   (void*)(smem + (B) * 49152 + (w * 8 + (CC) * 2) * 512       \
                           + lane * 16));                                      \
    }
    // stage W call CC (0..1) of K-tile IT into buffer B (W part at +32768)
#define STAGE_W(B, IT, CC)                                                     \
    {                                                                          \
        int off = (w * 2 + (CC)) * 1024 + lane * 16;                           \
        load_lds16((const void*)(wslab + (size_t)(IT) * 16384 + off),          \
                   (void*)(smem + (B) * 49152 + 32768 + off));                 \
    }
#define LDPAIR(dst, base, d)                                                   \
    {                                                                          \
        i32x4 lo_ = *(const i32x4*)(base);                                     \
        i32x4 hi_ = *(const i32x4*)((base) + (d));                             \
        dst = __builtin_shufflevector(lo_, hi_, 0, 1, 2, 3, 4, 5, 6, 7);       \
    }

    // ---- prologue ----
    if constexpr (nIt > 1) {
        STAGE_A(0, 0, 0) STAGE_A(0, 0, 1) STAGE_A(0, 0, 2) STAGE_A(0, 0, 3)
        STAGE_W(0, 0, 0) STAGE_W(0, 0, 1)
        FENCE;
        STAGE_A(1, 1, 0) STAGE_A(1, 1, 1) STAGE_A(1, 1, 2) STAGE_A(1, 1, 3)
        STAGE_W(1, 1, 0) STAGE_W(1, 1, 1)
        FENCE;
        asm volatile("s_waitcnt vmcnt(6)" ::: "memory");  // tile0 landed; tile1 flies
    } else {
        STAGE_A(0, 0, 0) STAGE_A(0, 0, 1) STAGE_A(0, 0, 2) STAGE_A(0, 0, 3)
        STAGE_W(0, 0, 0) STAGE_W(0, 0, 1)
        FENCE;
        asm volatile("s_waitcnt vmcnt(0)" ::: "memory");
    }
    __builtin_amdgcn_s_barrier();

    // ---- K-iter: 2 fat phases, all indices compile-time literals ----
#define GEMM_ITER(IT, CB, SB, HA, HW)                                          \
    {                                                                          \
        const u8* Ab = smem + (CB) * 49152;                                    \
        const u8* Wb = Ab + 32768;                                             \
        i32x8 bf0, bf1;                                                        \
        LDPAIR(bf0, Wb + (wn * 2 + 0) * 2048 + lane * 16, 1024)                \
        LDPAIR(bf1, Wb + (wn * 2 + 1) * 2048 + lane * 16, 1024)                \
        {                                                                      \
            i32x8 a0, a1, a2, a3;                                              \
            LDPAIR(a0, Ab + (wm2 * 8 + 0) * 2048 + lane * 32, 16)              \
            LDPAIR(a1, Ab + (wm2 * 8 + 1) * 2048 + lane * 32, 16)              \
            LDPAIR(a2, Ab + (wm2 * 8 + 2) * 2048 + lane * 32, 16)              \
            LDPAIR(a3, Ab + (wm2 * 8 + 3) * 2048 + lane * 32, 16)              \
            if (HW) {                                                          \
                FENCE;                                                         \
                STAGE_A(SB, (IT) + 2, 0) STAGE_A(SB, (IT) + 2, 1)              \
                STAGE_W(SB, (IT) + 2, 0)                                       \
                FENCE;                                                         \
            }                                                                  \
            __builtin_amdgcn_s_barrier();                                      \
            __builtin_amdgcn_s_setprio(1);                                     \
            acc[0][0] = mfma128(bf0, a0, acc[0][0]);                           \
            acc[0][1] = mfma128(bf1, a0, acc[0][1]);                           \
            acc[1][0] = mfma128(bf0, a1, acc[1][0]);                           \
            acc[1][1] = mfma128(bf1, a1, acc[1][1]);                           \
            acc[2][0] = mfma128(bf0, a2, acc[2][0]);                           \
            acc[2][1] = mfma128(bf1, a2, acc[2][1]);                           \
            acc[3][0] = mfma128(bf0, a3, acc[3][0]);                           \
            acc[3][1] = mfma128(bf1, a3, acc[3][1]);                           \
            __builtin_amdgcn_s_setprio(0);                                     \
            __builtin_amdgcn_s_barrier();                                      \
        }                                                                      \
        {                                                                      \
            i32x8 a4, a5, a6, a7;                                              \
            LDPAIR(a4, Ab + (wm2 * 8 + 4) * 2048 + lane * 32, 16)              \
            LDPAIR(a5, Ab + (wm2 * 8 + 5) * 2048 + lane * 32, 16)              \
            LDPAIR(a6, Ab + (wm2 * 8 + 6) * 2048 + lane * 32, 16)              \
            LDPAIR(a7, Ab + (wm2 * 8 + 7) * 2048 + lane * 32, 16)              \
            if (HW) {                                                          \
                FENCE;                                                         \
                STAGE_A(SB, (IT) + 2, 2) STAGE_A(SB, (IT) + 2, 3)              \
                STAGE_W(SB, (IT) + 2, 1)                                       \
                FENCE;                                                         \
            }                                                                  \
            __builtin_amdgcn_s_barrier();                                      \
            __builtin_amdgcn_s_setprio(1);                                     \
            acc[4][0] = mfma128(bf0, a4, acc[4][0]);                           \
            acc[4][1] = mfma128(bf1, a4, acc[4][1]);                           \
            acc[5][0] = mfma128(bf0, a5, acc[5][0]);                           \
            acc[5][1] = mfma128(bf1, a5, acc[5][1]);                           \
            acc[6][0] = mfma128(bf0, a6, acc[6][0]);                           \
            acc[6][1] = mfma128(bf1, a6, acc[6][1]);                           \
            acc[7][0] = mfma128(bf0, a7, acc[7][0]);                           \
            acc[7][1] = mfma128(bf1, a7, acc[7][1]);                           \
            __builtin_amdgcn_s_setprio(0);                                     \
            if (HA) {                                                          \
                if (HW) asm volatile("s_waitcnt vmcnt(6)" ::: "memory");       \
                else    asm volatile("s_waitcnt vmcnt(0)" ::: "memory");       \
            }                                                                  \
            __builtin_amdgcn_s_barrier();                                      \
        }                                                                      \
    }

    if constexpr (nIt == 8) {
        GEMM_ITER(0, 0, 2, true,  true)
        GEMM_ITER(1, 1, 0, true,  true)
        GEMM_ITER(2, 2, 1, true,  true)
        GEMM_ITER(3, 0, 2, true,  true)
        GEMM_ITER(4, 1, 0, true,  true)
        GEMM_ITER(5, 2, 1, true,  true)
        GEMM_ITER(6, 0, 2, true,  false)
        GEMM_ITER(7, 1, 0, false, false)
    } else {
        static_assert(KT == K0P, "unexpected KT");
        GEMM_ITER(0, 0, 0, false, false)
    }
#undef GEMM_ITER
#undef STAGE_A
#undef STAGE_W
#undef LDPAIR

    // lane element (i,jj,r): m = bm*256 + wm2*128 + i*16 + r16,
    //                        n = bn*128 + wn*32 + jj*16 + q*4 + r
    if constexpr (MODE == 0) {
        // Repack to next layer's A_t. eb tile: [m16l(16)][c32l=wn(4)][512B].
        __syncthreads();
        u8* eb = smem;
#pragma unroll
        for (int i = 0; i < 8; i++) {
#pragma unroll
            for (int jj = 0; jj < 2; jj++) {
                int nl = wn * 32 + jj * 16 + q * 4;
                f32x4 b4 = *(const f32x4*)(bb + bn * 128 + nl);
                float v0 = fmaxf(acc[i][jj][0] + b4[0], 0.0f);
                float v1 = fmaxf(acc[i][jj][1] + b4[1], 0.0f);
                float v2 = fmaxf(acc[i][jj][2] + b4[2], 0.0f);
                float v3 = fmaxf(acc[i][jj][3] + b4[3], 0.0f);
                int p = __builtin_amdgcn_cvt_pk_fp8_f32(v0, v1, 0, false);
                p     = __builtin_amdgcn_cvt_pk_fp8_f32(v2, v3, p, true);
                int m16l = wm2 * 8 + i;
                int idx = ((m16l * 4 + wn) * 16 + r16) * 32 + jj * 16 + q * 4;
                *(int*)(eb + idx) = p;
            }
        }
        __syncthreads();
#pragma unroll
        for (int rd = 0; rd < 4; rd++) {
            int g2  = rd * 512 + t;            // dwordx4 index 0..2047
            int seg = g2 >> 5, off = (g2 & 31) * 16;
            i32x4 v = *(const i32x4*)(eb + seg * 512 + off);
            *(i32x4*)(O + ((size_t)((bm * 16 + (seg >> 2)) * 32 + bn * 4
                                    + (seg & 3))) * 512 + off) = v;
        }
    } else {
        __syncthreads();
        float* red = (float*)smem;             // [256 rows][4 wn][3] = 12 KB
#pragma unroll
        for (int i = 0; i < 8; i++) {
            float p0 = 0.f, p1 = 0.f, p2 = 0.f;
#pragma unroll
            for (int jj = 0; jj < 2; jj++) {
                int nb = bn * 128 + wn * 32 + jj * 16 + q * 4;
                f32x4 b4 = *(const f32x4*)(bb + nb);
#pragma unroll
                for (int r = 0; r < 4; r++) {
                    float val = fmaxf(acc[i][jj][r] + b4[r], 0.0f);
                    const float* wo = Wout + (size_t)(nb + r) * NV;
                    p0 += val * wo[0]; p1 += val * wo[1]; p2 += val * wo[2];
                }
            }
            // reduce over the 4 q-lanes (lane bits 4,5) holding the same m
            p0 += __shfl_xor(p0, 16); p0 += __shfl_xor(p0, 32);
            p1 += __shfl_xor(p1, 16); p1 += __shfl_xor(p1, 32);
            p2 += __shfl_xor(p2, 16); p2 += __shfl_xor(p2, 32);
            if (q == 0) {
                int row = (wm2 * 8 + i) * 16 + r16;   // m-local 0..255
                int base = (row * 4 + wn) * 3;
                red[base + 0] = p0; red[base + 1] = p1; red[base + 2] = p2;
            }
        }
        __syncthreads();
        if (t < 256) {
            int row = t;
            float s0 = 0.f, s1 = 0.f, s2 = 0.f;
#pragma unroll
            for (int c = 0; c < 4; c++) {
                s0 += red[(row * 4 + c) * 3 + 0];
                s1 += red[(row * 4 + c) * 3 + 1];
                s2 += red[(row * 4 + c) * 3 + 2];
            }
            int m = bm * 256 + row;
            atomicAdd(&out[(size_t)m * NV + 0], s0);
            atomicAdd(&out[(size_t)m * NV + 1], s1);
            atomicAdd(&out[(size_t)m * NV + 2], s2);
        }
    }
#undef FENCE
}

// ---------------------------------------------------------------------------
extern "C" void kernel_launch(void* const* d_in, const int* in_sizes, int n_in,
                              void* d_out, int out_size, void* d_ws, size_t ws_size,
                              hipStream_t stream) {
    const float* coords     = (const float*)d_in[0];
    const int*   latent_idx = (const int*)d_in[1];
    const float* latents    = (const float*)d_in[2];
    const float* codebooks  = (const float*)d_in[3];
    const float* mod_W      = (const float*)d_in[4];
    const float* mod_b      = (const float*)d_in[5];
    const float* dec_W0     = (const float*)d_in[6];
    const float* dec_b0     = (const float*)d_in[7];
    const float* dec_Wh     = (const float*)d_in[8];
    const float* dec_bh     = (const float*)d_in[9];
    const float* dec_Wout   = (const float*)d_in[10];
    const float* dec_bout   = (const float*)d_in[11];
    float* out = (float*)d_out;

    // ---- workspace layout (fixed part ~4.35 MB) ----
    char* wsb = (char*)d_ws;
    float* zq  = (float*)(wsb + 0);                        //      256 B
    float* bb  = (float*)(wsb + 256);                      //   20,480 B
    u8*    W0T = (u8*)(wsb + 20736);                       //  131,072 B  tiled
    u8*    WhT = (u8*)(wsb + 151808);                      // 4,194,304 B tiled
    const size_t fixed_end = 4346368;                      // 256-aligned

    // adaptive chunk: cap 65536 (single chunk, ws ~139 MB), halve until fits;
    // floor 2048 so Mb = Bc/256 stays a multiple of 8 (capture-safe).
    int Bc = 65536;
    while (Bc > 2048 && fixed_end + 2 * (size_t)Bc * NH > ws_size)
        Bc >>= 1;
    int Mb = Bc / 256;   // m-tiles of 256

    u8* hA = (u8*)(wsb + fixed_end);                       // [Bc][1024] fp8 A_t
    u8* hB = hA + (size_t)Bc * NH;                         // [Bc][1024] fp8 A_t
    u8* pe = hB;   // pe A_t [Bc][128] aliases hB (dead before layer-1 writes hB)

    // 144 KB dynamic LDS for the 8-wave triple-buffered GEMM
    const int LDS_BYTES = 147456;
    hipFuncSetAttribute(reinterpret_cast<const void*>(gemm_kernel<0, K0P>),
                        hipFuncAttributeMaxDynamicSharedMemorySize, LDS_BYTES);
    hipFuncSetAttribute(reinterpret_cast<const void*>(gemm_kernel<0, NH>),
                        hipFuncAttributeMaxDynamicSharedMemorySize, LDS_BYTES);
    hipFuncSetAttribute(reinterpret_cast<const void*>(gemm_kernel<1, NH>),
                        hipFuncAttributeMaxDynamicSharedMemorySize, LDS_BYTES);

    // ---- one-time (per call) small kernels ----
    vq_kernel<<<1, 1024, 0, stream>>>(latents, latent_idx, codebooks, zq, out);
    betas_kernel<<<20, 256, 0, stream>>>(zq, mod_W, mod_b, dec_b0, dec_bh, bb);
    init_out_kernel<<<(NB * NV) / 256, 256, 0, stream>>>(dec_bout, out);
    prep_kernel<<<dim3(4, 32, 1), dim3(32, 8), 0, stream>>>(dec_W0, W0T, NIN, K0P);
    prep_kernel<<<dim3(32, 32, 4), dim3(32, 8), 0, stream>>>(dec_Wh, WhT, NH, NH);

    // ---- chunked 5-layer MLP, output layer fused into the last GEMM ----
    for (int c0 = 0; c0 < NB; c0 += Bc) {
        pe_kernel<<<(Bc * 32) / 256, 256, 0, stream>>>(coords + (size_t)c0 * NC, pe);
        gemm_kernel<0, K0P><<<8 * Mb, 512, LDS_BYTES, stream>>>(
            pe, W0T, bb + 0 * NH, hA, nullptr, nullptr, Mb);
        gemm_kernel<0, NH><<<8 * Mb, 512, LDS_BYTES, stream>>>(
            hA, WhT + 0 * (size_t)NH * NH, bb + 1 * NH, hB, nullptr, nullptr, Mb);
        gemm_kernel<0, NH><<<8 * Mb, 512, LDS_BYTES, stream>>>(
            hB, WhT + 1 * (size_t)NH * NH, bb + 2 * NH, hA, nullptr, nullptr, Mb);
        gemm_kernel<0, NH><<<8 * Mb, 512, LDS_BYTES, stream>>>(
            hA, WhT + 2 * (size_t)NH * NH, bb + 3 * NH, hB, nullptr, nullptr, Mb);
        gemm_kernel<1, NH><<<8 * Mb, 512, LDS_BYTES, stream>>>(
            hB, WhT + 3 * (size_t)NH * NH, bb + 4 * NH, nullptr,
            dec_Wout, out + (size_t)c0 * NV, Mb);
    }
}

// Round 5
// 515.072 us; speedup vs baseline: 1.3431x; 1.3431x over previous
//
#include <hip/hip_runtime.h>
#include <hip/hip_bf16.h>
#include <stdint.h>

// ---- problem constants ----
#define NB   65536      // batch points
#define NC   2
#define NV   3
#define ND   64
#define NK   1024       // codebook entries
#define NS   4
#define NH   1024
#define NL   5
#define NF   25
#define NIN  102
#define K0P  128        // padded layer-0 K

typedef float f32x4 __attribute__((ext_vector_type(4)));
typedef int   i32x4 __attribute__((ext_vector_type(4)));
typedef int   i32x8 __attribute__((ext_vector_type(8)));
typedef unsigned char u8;

__device__ __forceinline__ void load_lds16(const void* g, void* l) {
    __builtin_amdgcn_global_load_lds(
        (const __attribute__((address_space(1))) void*)g,
        (__attribute__((address_space(3))) void*)l,
        16, 0, 0);
}

// fp8 e4m3 scalar convert (RNE, saturating): low byte of cvt_pk
__device__ __forceinline__ u8 to_fp8(float x) {
    return (u8)(__builtin_amdgcn_cvt_pk_fp8_f32(x, 0.0f, 0, false) & 0xff);
}

__device__ __forceinline__ f32x4 mfma128(i32x8 wf, i32x8 af, f32x4 c) {
    // swapped operands: D rows (q*4+r) = n-dim, cols (r16) = m-dim
    return __builtin_amdgcn_mfma_scale_f32_16x16x128_f8f6f4(
        wf, af, c, 0, 0,
        0, 0x79797979,    // scale src0 (W): 2^-6
        0, 0x7f7f7f7f);   // scale src1 (A): 2^0
}

// ===========================================================================
// TILED OPERAND LAYOUTS (R17)
//  W_t (unchanged): flat = (((bn*nIt + it)*8 + j)*2 + half)*1024
//                          + (q*16+r16)*16 + b16
//       holds W[n][k]: n = bn*128 + j*16 + r16,
//                      k = it*128 + q*32 + half*16 + b16.
//       Per-(bn,it) slab = 16 KB contiguous; frag read = 2 x b128 at
//       lane*16 / +1024 (conflict-free).
//  A_t (NEW, half-split like W_t): flat = ((m16*nIt + it)*2 + half)*1024
//                          + (q*16+r16)*16 + b16
//       holds A[m][k]: m = m16*16 + r16, k = it*128 + q*32 + half*16 + b16.
//       Per-(m16,it) slab = 2 KB contiguous -> linear gload_lds staging AND
//       conflict-free lane*16 frag reads (R16's lane*32 A-read was a 16-way
//       bank conflict, 8.8M conflict cycles/dispatch).
// ===========================================================================

// ---------------------------------------------------------------------------
// VQ kernel: single block, 1024 threads (one codebook row per thread). fp32.
// ---------------------------------------------------------------------------
__global__ __launch_bounds__(1024) void vq_kernel(
    const float* __restrict__ latents, const int* __restrict__ latent_idx,
    const float* __restrict__ codebooks, float* __restrict__ zq_out,
    float* __restrict__ out) {
    __shared__ float zcur[ND], resid[ND], zqsum[ND], ssq[ND];
    __shared__ float sDw[16];
    __shared__ int   sKw[16];
    __shared__ int   sBest;
    int t = threadIdx.x, lane = t & 63, wv = t >> 6;
    const float* img = latents + (size_t)latent_idx[0] * (NS * ND);
    if (t < ND) { resid[t] = 0.f; zqsum[t] = 0.f; }
    __syncthreads();
    float lossAcc = 0.f;   // thread 0 only
    for (int s = 0; s < NS; s++) {
        if (t < ND) {
            float iv = img[s * ND + t];
            float r  = resid[t] + iv;
            resid[t] = r;
            zcur[t]  = (s == 0) ? iv : (r - zqsum[t]);
        }
        __syncthreads();
        float zz = 0.f;
#pragma unroll
        for (int d = 0; d < ND; d++) { float z = zcur[d]; zz += z * z; }
        const float4* e4 = (const float4*)(codebooks + ((size_t)s * NK + t) * ND);
        float dot = 0.f, ee = 0.f;
#pragma unroll
        for (int i = 0; i < 16; i++) {
            float4 v = e4[i];
            dot += zcur[4 * i + 0] * v.x; dot += zcur[4 * i + 1] * v.y;
            dot += zcur[4 * i + 2] * v.z; dot += zcur[4 * i + 3] * v.w;
            ee  += v.x * v.x; ee += v.y * v.y; ee += v.z * v.z; ee += v.w * v.w;
        }
        float dmin = zz - 2.0f * dot + ee;
        int   kmin = t;
#pragma unroll
        for (int m = 1; m < 64; m <<= 1) {
            float d2 = __shfl_xor(dmin, m);
            int   k2 = __shfl_xor(kmin, m);
            if (d2 < dmin || (d2 == dmin && k2 < kmin)) { dmin = d2; kmin = k2; }
        }
        if (lane == 0) { sDw[wv] = dmin; sKw[wv] = kmin; }
        __syncthreads();
        if (t == 0) {
            float bd = sDw[0]; int bk = sKw[0];
            for (int w = 1; w < 16; w++) {
                float d2 = sDw[w]; int k2 = sKw[w];
                if (d2 < bd || (d2 == bd && k2 < bk)) { bd = d2; bk = k2; }
            }
            sBest = bk;
            out[NB * NV + s] = (float)bk;
        }
        __syncthreads();
        int best = sBest;
        const float* eb = codebooks + ((size_t)s * NK + best) * ND;
        if (t < ND) {
            float zq = eb[t];
            float d  = zq - zcur[t];
            ssq[t]   = d * d;
            zqsum[t] = zqsum[t] + (zq + (zcur[t] - zq));   // z_q_st forward (exact ref arith)
        }
        __syncthreads();
        if (t == 0) {
            float sum = 0.f;
            for (int d = 0; d < ND; d++) sum += ssq[d];
            lossAcc += 0.25f * (sum / (float)ND);
        }
    }
    if (t < ND) zq_out[t] = zqsum[t];
    if (t == 0) out[NB * NV + NS] = lossAcc;
}

// ---------------------------------------------------------------------------
// betas fused with decoder biases (fp32)
// ---------------------------------------------------------------------------
__global__ __launch_bounds__(256) void betas_kernel(
    const float* __restrict__ zq, const float* __restrict__ mod_W,
    const float* __restrict__ mod_b, const float* __restrict__ b0,
    const float* __restrict__ bh, float* __restrict__ bb) {
    int g = blockIdx.x * 256 + threadIdx.x;   // < 5120
    int l = g >> 10, n = g & 1023;
    float acc = mod_b[g];
    for (int d = 0; d < ND; d++) acc += zq[d] * mod_W[(size_t)(l * ND + d) * NH + n];
    acc += (l == 0) ? b0[n] : bh[(size_t)(l - 1) * NH + n];
    bb[g] = acc;
}

// ---------------------------------------------------------------------------
// out init: values[m][v] = bout[v] (atomic-add target for the fused layer)
// ---------------------------------------------------------------------------
__global__ __launch_bounds__(256) void init_out_kernel(
    const float* __restrict__ bout, float* __restrict__ out) {
    int g = blockIdx.x * 256 + threadIdx.x;   // < NB*NV
    out[g] = bout[g % NV];
}

// ---------------------------------------------------------------------------
// Weight prep: fp32 [Ks][1024] -> fp8 e4m3 W_t tiled (x64, undone by the
// MFMA e8m0 scale 2^-6). Zero-pad k>=Ks. nIt = Kp/128. Half-split layout.
// ---------------------------------------------------------------------------
__global__ __launch_bounds__(256) void prep_kernel(
    const float* __restrict__ src, u8* __restrict__ dst, int Ks, int Kp) {
    __shared__ float tile[32][33];
    int nIt = Kp >> 7;
    src += (size_t)blockIdx.z * Ks * NH;
    dst += (size_t)blockIdx.z * NH * Kp;
    int k0 = blockIdx.x * 32, n0 = blockIdx.y * 32;
    int tx = threadIdx.x, ty = threadIdx.y;   // (32, 8)
    for (int i = 0; i < 4; i++) {
        int k = k0 + ty + i * 8;
        int n = n0 + tx;
        tile[ty + i * 8][tx] = (k < Ks) ? src[(size_t)k * NH + n] : 0.0f;
    }
    __syncthreads();
    for (int i = 0; i < 4; i++) {
        int n = n0 + ty + i * 8;
        int k = k0 + tx;
        int bn = n >> 7, j = (n >> 4) & 7, r16 = n & 15;
        int it = k >> 7, q = (k >> 5) & 3, half = (k >> 4) & 1, b16 = k & 15;
        size_t flat = ((size_t)(((bn * nIt + it) * 8 + j) * 2 + half)) * 1024
                    + (q * 16 + r16) * 16 + b16;
        dst[flat] = to_fp8(tile[tx][ty + i * 8] * 64.0f);
    }
}

// ---------------------------------------------------------------------------
// Positional encoding -> fp8 A_t (NEW half-split layout, K=128, nIt=1)
// ---------------------------------------------------------------------------
__device__ __forceinline__ float pe_val(const float* coords, int m, int k) {
    if (k < 2) return coords[m * 2 + k];
    if (k >= NIN) return 0.0f;
    int u = k - 2;
    int f = u >> 2, r = u & 3;
    float c = coords[m * 2 + (r & 1)];
    float a = c * __builtin_ldexpf(3.14159274101257324f, f);
    return (r < 2) ? sinf(a) : cosf(a);
}

__global__ __launch_bounds__(256) void pe_kernel(
    const float* __restrict__ coords, u8* __restrict__ pe) {
    int g = blockIdx.x * 256 + threadIdx.x;   // < Bc*32
    int m = g >> 5, k4 = (g & 31) * 4;
    float v0 = pe_val(coords, m, k4 + 0);
    float v1 = pe_val(coords, m, k4 + 1);
    float v2 = pe_val(coords, m, k4 + 2);
    float v3 = pe_val(coords, m, k4 + 3);
    int p = __builtin_amdgcn_cvt_pk_fp8_f32(v0, v1, 0, false);
    p     = __builtin_amdgcn_cvt_pk_fp8_f32(v2, v3, p, true);
    // A_t half-split (nIt=1): ((m16*1+0)*2 + half)*1024 + (q*16+r16)*16 + b16
    int m16 = m >> 4, r16 = m & 15;
    int q = k4 >> 5, half = (k4 >> 4) & 1, b16 = k4 & 15;
    *(int*)(pe + ((size_t)(m16 * 2 + half)) * 1024 + (q * 16 + r16) * 16 + b16) = p;
}

// ---------------------------------------------------------------------------
// MX-fp8 MFMA GEMM, R17: 8-wave 4-phase schedule, conflict-free + fenced.
// Fixes R16's three measured failures:
//  (1) A_t half-split layout -> A frag ds_read at lane*16 (0 bank conflicts;
//      R16's lane*32 was 16-way).
//  (2) sched_barrier(0) walls after every s_barrier + lgkmcnt(0)+sched_barrier
//      before each MFMA cluster -> no cross-phase hoisting of LDS reads (raw
//      s_barrier has NO compiler memory semantics; R16's reads migrated,
//      live ranges merged, spill -> 475 MB scratch).
//  (3) wave tile 64x64 (acc 64 AGPR + frags 64 VGPR ~ 150 live << 256 cap).
// Structure: block 256m x 128n, 8 waves 4M x 2N, BK=128, triple-buffered
// 48 KB tiles (144 KB dynamic LDS, 1 block/CU, 2 waves/SIMD co-resident).
// Per iter: 4 phases x {ds-read 2 frag-pairs; 1-2 gload_lds; s_barrier;
// lgkmcnt(0); setprio(1); 4 MFMA; setprio(0); s_barrier} with ONE counted
// vmcnt(6) per iter at the phase-3 boundary (tile it+2's 6 stage ops stay in
// flight; never 0 in the main loop). Loop VMEM = staging only -> exact count.
// MODE 0: relu(acc+bb) -> fp8, repack to next layer's A_t via LDS, coalesced.
// MODE 1: out[m][v] += relu(acc+bb).Wout[n][v], q-shfl + LDS wn-reduce.
// ---------------------------------------------------------------------------
template <int MODE, int KT>
__global__ __launch_bounds__(512, 2) void gemm_kernel(
    const u8* __restrict__ A, const u8* __restrict__ W,
    const float* __restrict__ bb, u8* __restrict__ O,
    const float* __restrict__ Wout, float* __restrict__ out, int Mb) {
    extern __shared__ __align__(16) u8 smem[];   // 3 x 49152
    int t   = threadIdx.x;
    int fid = blockIdx.x;
    int xcd = fid & 7;
    int j8  = fid >> 3;                 // 0..Mb-1
    int bn  = j8 & 7;                   // fastest within an XCD
    int bm  = xcd * (Mb >> 3) + (j8 >> 3);   // 256-row m-tile index
    int lane = t & 63, w = t >> 6;      // 8 waves
    int wm4  = w >> 1, wn = w & 1;      // 4 m-quarters x 2 n-halves
    int q    = lane >> 4, r16 = lane & 15;
    constexpr int nIt = KT >> 7;

    const u8* wslab = W + (size_t)(bn * nIt) * 16384;

    f32x4 acc[4][4];
    f32x4 zero = {0.f, 0.f, 0.f, 0.f};
    for (int i = 0; i < 4; i++)
        for (int j = 0; j < 4; j++) acc[i][j] = zero;

#define FENCE asm volatile("" ::: "memory")
#define SBAR  __builtin_amdgcn_s_barrier()
#define SCHED __builtin_amdgcn_sched_barrier(0)
#define LGKM0 asm volatile("s_waitcnt lgkmcnt(0)" ::: "memory")

    // stage A inst S (0..3) of K-tile IT into buffer B (8 KB each, linear)
#define STAGE_A(B, IT, S)                                                      \
    {                                                                          \
        int g_ = (S) * 512 + t;                                                \
        load_lds16((const void*)(A + ((size_t)(bm * 16 + (g_ >> 7)) * nIt      \
                                      + (IT)) * 2048 + (g_ & 127) * 16),       \
                   (void*)(smem + (B) * 49152 + g_ * 16));                     \
    }
    // stage W inst S (0..1) of K-tile IT into buffer B (8 KB each, linear)
#define STAGE_W(B, IT, S)                                                      \
    {                                                                          \
        int g_ = (S) * 512 + t;                                                \
        load_lds16((const void*)(wslab + (size_t)(IT) * 16384 + g_ * 16),      \
                   (void*)(smem + (B) * 49152 + 32768 + g_ * 16));             \
    }
#define LDPAIR(dst, base)                                                      \
    {                                                                          \
        i32x4 lo_ = *(const i32x4*)(base);                                     \
        i32x4 hi_ = *(const i32x4*)((base) + 1024);                            \
        dst = __builtin_shufflevector(lo_, hi_, 0, 1, 2, 3, 4, 5, 6, 7);       \
    }

    // ---- prologue: stage tile0 [, tile1]; wait tile0 ----
    STAGE_A(0, 0, 0) STAGE_A(0, 0, 1) STAGE_A(0, 0, 2) STAGE_A(0, 0, 3)
    STAGE_W(0, 0, 0) STAGE_W(0, 0, 1)
    FENCE;
    if constexpr (nIt > 1) {
        STAGE_A(1, 1, 0) STAGE_A(1, 1, 1) STAGE_A(1, 1, 2) STAGE_A(1, 1, 3)
        STAGE_W(1, 1, 0) STAGE_W(1, 1, 1)
        FENCE;
        asm volatile("s_waitcnt vmcnt(6)" ::: "memory");  // tile0 landed
    } else {
        asm volatile("s_waitcnt vmcnt(0)" ::: "memory");
    }
    SBAR;
    SCHED;

    // ---- K-iter: 4 phases, literal buffer indices, hard phase walls ----
#define GEMM_ITER(IT, CB, SB, HA, HW)                                          \
    {                                                                          \
        const u8* Ab = smem + (CB) * 49152;                                    \
        const u8* Wb = Ab + 32768;                                             \
        i32x8 A0, A1, A2, A3, W0, W1, W2, W3;                                  \
        /* P0 */                                                               \
        LDPAIR(A0, Ab + (wm4 * 4 + 0) * 2048 + lane * 16)                      \
        LDPAIR(A1, Ab + (wm4 * 4 + 1) * 2048 + lane * 16)                      \
        LDPAIR(W0, Wb + (wn * 4 + 0) * 2048 + lane * 16)                       \
        LDPAIR(W1, Wb + (wn * 4 + 1) * 2048 + lane * 16)                       \
        if (HW) { FENCE; STAGE_A(SB, (IT) + 2, 0) STAGE_A(SB, (IT) + 2, 1) FENCE; } \
        SBAR; LGKM0; SCHED;                                                    \
        __builtin_amdgcn_s_setprio(1);                                         \
        acc[0][0] = mfma128(W0, A0, acc[0][0]);                                \
        acc[1][0] = mfma128(W0, A1, acc[1][0]);                                \
        acc[0][1] = mfma128(W1, A0, acc[0][1]);                                \
        acc[1][1] = mfma128(W1, A1, acc[1][1]);                                \
        __builtin_amdgcn_s_setprio(0);                                         \
        SBAR; SCHED;                                                           \
        /* P1 */                                                               \
        LDPAIR(A2, Ab + (wm4 * 4 + 2) * 2048 + lane * 16)                      \
        LDPAIR(A3, Ab + (wm4 * 4 + 3) * 2048 + lane * 16)                      \
        if (HW) { FENCE; STAGE_A(SB, (IT) + 2, 2) STAGE_A(SB, (IT) + 2, 3) FENCE; } \
        SBAR; LGKM0; SCHED;                                                    \
        __builtin_amdgcn_s_setprio(1);                                         \
        acc[2][0] = mfma128(W0, A2, acc[2][0]);                                \
        acc[3][0] = mfma128(W0, A3, acc[3][0]);                                \
        acc[2][1] = mfma128(W1, A2, acc[2][1]);                                \
        acc[3][1] = mfma128(W1, A3, acc[3][1]);                                \
        __builtin_amdgcn_s_setprio(0);                                         \
        SBAR; SCHED;                                                           \
        /* P2 */                                                               \
        LDPAIR(W2, Wb + (wn * 4 + 2) * 2048 + lane * 16)                       \
        LDPAIR(W3, Wb + (wn * 4 + 3) * 2048 + lane * 16)                       \
        if (HW) { FENCE; STAGE_W(SB, (IT) + 2, 0) STAGE_W(SB, (IT) + 2, 1) FENCE; } \
        SBAR; LGKM0; SCHED;                                                    \
        __builtin_amdgcn_s_setprio(1);                                         \
        acc[0][2] = mfma128(W2, A0, acc[0][2]);                                \
        acc[1][2] = mfma128(W2, A1, acc[1][2]);                                \
        acc[0][3] = mfma128(W3, A0, acc[0][3]);                                \
        acc[1][3] = mfma128(W3, A1, acc[1][3]);                                \
        __builtin_amdgcn_s_setprio(0);                                         \
        SBAR; SCHED;                                                           \
        /* P3 */                                                               \
        __builtin_amdgcn_s_setprio(1);                                         \
        acc[2][2] = mfma128(W2, A2, acc[2][2]);                                \
        acc[3][2] = mfma128(W2, A3, acc[3][2]);                                \
        acc[2][3] = mfma128(W3, A2, acc[2][3]);                                \
        acc[3][3] = mfma128(W3, A3, acc[3][3]);                                \
        __builtin_amdgcn_s_setprio(0);                                         \
        if (HA) {                                                              \
            if (HW) asm volatile("s_waitcnt vmcnt(6)" ::: "memory");           \
            else    asm volatile("s_waitcnt vmcnt(0)" ::: "memory");           \
        }                                                                      \
        SBAR; SCHED;                                                           \
    }

    if constexpr (nIt == 8) {
        GEMM_ITER(0, 0, 2, true,  true)
        GEMM_ITER(1, 1, 0, true,  true)
        GEMM_ITER(2, 2, 1, true,  true)
        GEMM_ITER(3, 0, 2, true,  true)
        GEMM_ITER(4, 1, 0, true,  true)
        GEMM_ITER(5, 2, 1, true,  true)
        GEMM_ITER(6, 0, 2, true,  false)
        GEMM_ITER(7, 1, 0, false, false)
    } else {
        static_assert(KT == K0P, "unexpected KT");
        GEMM_ITER(0, 0, 0, false, false)
    }
#undef GEMM_ITER
#undef STAGE_A
#undef STAGE_W
#undef LDPAIR

    // lane element (i,j,r): m = bm*256 + wm4*64 + i*16 + r16,
    //                       n = bn*128 + (wn*4 + j)*16 + q*4 + r
    if constexpr (MODE == 0) {
        // Repack to next layer's A_t (half-split, nIt'=8, it'=bn).
        // Local 32 KB: [m16l(16)][half(2)][1024B], inner (q'*16+r16)*16+b16.
        __syncthreads();
        u8* eb = smem;
#pragma unroll
        for (int i = 0; i < 4; i++) {
#pragma unroll
            for (int j = 0; j < 4; j++) {
                int nl = (wn * 4 + j) * 16 + q * 4;
                f32x4 b4 = *(const f32x4*)(bb + bn * 128 + nl);
                float v0 = fmaxf(acc[i][j][0] + b4[0], 0.0f);
                float v1 = fmaxf(acc[i][j][1] + b4[1], 0.0f);
                float v2 = fmaxf(acc[i][j][2] + b4[2], 0.0f);
                float v3 = fmaxf(acc[i][j][3] + b4[3], 0.0f);
                int p = __builtin_amdgcn_cvt_pk_fp8_f32(v0, v1, 0, false);
                p     = __builtin_amdgcn_cvt_pk_fp8_f32(v2, v3, p, true);
                int m16l = wm4 * 4 + i;
                int half = j & 1;
                int qp   = wn * 2 + (j >> 1);      // (n>>5)&3
                int idx  = (m16l * 2 + half) * 1024 + (qp * 16 + r16) * 16 + q * 4;
                *(int*)(eb + idx) = p;
            }
        }
        __syncthreads();
#pragma unroll
        for (int rd = 0; rd < 4; rd++) {
            int g2 = rd * 512 + t;                 // dwordx4 index 0..2047
            i32x4 v = *(const i32x4*)(eb + g2 * 16);
            *(i32x4*)(O + ((size_t)((bm * 16 + (g2 >> 7)) * 8 + bn)) * 2048
                      + (g2 & 127) * 16) = v;
        }
    } else {
        __syncthreads();
        float* red = (float*)smem;                 // [256][2][3] = 6 KB
#pragma unroll
        for (int i = 0; i < 4; i++) {
            float p0 = 0.f, p1 = 0.f, p2 = 0.f;
#pragma unroll
            for (int j = 0; j < 4; j++) {
                int nb = bn * 128 + (wn * 4 + j) * 16 + q * 4;
                f32x4 b4 = *(const f32x4*)(bb + nb);
#pragma unroll
                for (int r = 0; r < 4; r++) {
                    float val = fmaxf(acc[i][j][r] + b4[r], 0.0f);
                    const float* wo = Wout + (size_t)(nb + r) * NV;
                    p0 += val * wo[0]; p1 += val * wo[1]; p2 += val * wo[2];
                }
            }
            // reduce over the 4 q-lanes (lane bits 4,5) holding the same m
            p0 += __shfl_xor(p0, 16); p0 += __shfl_xor(p0, 32);
            p1 += __shfl_xor(p1, 16); p1 += __shfl_xor(p1, 32);
            p2 += __shfl_xor(p2, 16); p2 += __shfl_xor(p2, 32);
            if (q == 0) {
                int row = (wm4 * 4 + i) * 16 + r16;   // 0..255
                int base = (row * 2 + wn) * 3;
                red[base + 0] = p0; red[base + 1] = p1; red[base + 2] = p2;
            }
        }
        __syncthreads();
        if (t < 256) {
            float s0 = red[(t * 2 + 0) * 3 + 0] + red[(t * 2 + 1) * 3 + 0];
            float s1 = red[(t * 2 + 0) * 3 + 1] + red[(t * 2 + 1) * 3 + 1];
            float s2 = red[(t * 2 + 0) * 3 + 2] + red[(t * 2 + 1) * 3 + 2];
            int m = bm * 256 + t;
            atomicAdd(&out[(size_t)m * NV + 0], s0);
            atomicAdd(&out[(size_t)m * NV + 1], s1);
            atomicAdd(&out[(size_t)m * NV + 2], s2);
        }
    }
#undef FENCE
#undef SBAR
#undef SCHED
#undef LGKM0
}

// ---------------------------------------------------------------------------
extern "C" void kernel_launch(void* const* d_in, const int* in_sizes, int n_in,
                              void* d_out, int out_size, void* d_ws, size_t ws_size,
                              hipStream_t stream) {
    const float* coords     = (const float*)d_in[0];
    const int*   latent_idx = (const int*)d_in[1];
    const float* latents    = (const float*)d_in[2];
    const float* codebooks  = (const float*)d_in[3];
    const float* mod_W      = (const float*)d_in[4];
    const float* mod_b      = (const float*)d_in[5];
    const float* dec_W0     = (const float*)d_in[6];
    const float* dec_b0     = (const float*)d_in[7];
    const float* dec_Wh     = (const float*)d_in[8];
    const float* dec_bh     = (const float*)d_in[9];
    const float* dec_Wout   = (const float*)d_in[10];
    const float* dec_bout   = (const float*)d_in[11];
    float* out = (float*)d_out;

    // ---- workspace layout (fixed part ~4.35 MB) ----
    char* wsb = (char*)d_ws;
    float* zq  = (float*)(wsb + 0);                        //      256 B
    float* bb  = (float*)(wsb + 256);                      //   20,480 B
    u8*    W0T = (u8*)(wsb + 20736);                       //  131,072 B  tiled
    u8*    WhT = (u8*)(wsb + 151808);                      // 4,194,304 B tiled
    const size_t fixed_end = 4346368;                      // 256-aligned

    // adaptive chunk: cap 65536 (single chunk, ws ~139 MB), halve until fits;
    // floor 2048 so Mb = Bc/256 stays a multiple of 8 (capture-safe).
    int Bc = 65536;
    while (Bc > 2048 && fixed_end + 2 * (size_t)Bc * NH > ws_size)
        Bc >>= 1;
    int Mb = Bc / 256;   // m-tiles of 256

    u8* hA = (u8*)(wsb + fixed_end);                       // [Bc][1024] fp8 A_t
    u8* hB = hA + (size_t)Bc * NH;                         // [Bc][1024] fp8 A_t
    u8* pe = hB;   // pe A_t [Bc][128] aliases hB (dead before layer-1 writes hB)

    // 144 KB dynamic LDS for the triple-buffered GEMM
    const int LDS_BYTES = 147456;
    hipFuncSetAttribute(reinterpret_cast<const void*>(gemm_kernel<0, K0P>),
                        hipFuncAttributeMaxDynamicSharedMemorySize, LDS_BYTES);
    hipFuncSetAttribute(reinterpret_cast<const void*>(gemm_kernel<0, NH>),
                        hipFuncAttributeMaxDynamicSharedMemorySize, LDS_BYTES);
    hipFuncSetAttribute(reinterpret_cast<const void*>(gemm_kernel<1, NH>),
                        hipFuncAttributeMaxDynamicSharedMemorySize, LDS_BYTES);

    // ---- one-time (per call) small kernels ----
    vq_kernel<<<1, 1024, 0, stream>>>(latents, latent_idx, codebooks, zq, out);
    betas_kernel<<<20, 256, 0, stream>>>(zq, mod_W, mod_b, dec_b0, dec_bh, bb);
    init_out_kernel<<<(NB * NV) / 256, 256, 0, stream>>>(dec_bout, out);
    prep_kernel<<<dim3(4, 32, 1), dim3(32, 8), 0, stream>>>(dec_W0, W0T, NIN, K0P);
    prep_kernel<<<dim3(32, 32, 4), dim3(32, 8), 0, stream>>>(dec_Wh, WhT, NH, NH);

    // ---- chunked 5-layer MLP, output layer fused into the last GEMM ----
    for (int c0 = 0; c0 < NB; c0 += Bc) {
        pe_kernel<<<(Bc * 32) / 256, 256, 0, stream>>>(coords + (size_t)c0 * NC, pe);
        gemm_kernel<0, K0P><<<8 * Mb, 512, LDS_BYTES, stream>>>(
            pe, W0T, bb + 0 * NH, hA, nullptr, nullptr, Mb);
        gemm_kernel<0, NH><<<8 * Mb, 512, LDS_BYTES, stream>>>(
            hA, WhT + 0 * (size_t)NH * NH, bb + 1 * NH, hB, nullptr, nullptr, Mb);
        gemm_kernel<0, NH><<<8 * Mb, 512, LDS_BYTES, stream>>>(
            hB, WhT + 1 * (size_t)NH * NH, bb + 2 * NH, hA, nullptr, nullptr, Mb);
        gemm_kernel<0, NH><<<8 * Mb, 512, LDS_BYTES, stream>>>(
            hA, WhT + 2 * (size_t)NH * NH, bb + 3 * NH, hB, nullptr, nullptr, Mb);
        gemm_kernel<1, NH><<<8 * Mb, 512, LDS_BYTES, stream>>>(
            hB, WhT + 3 * (size_t)NH * NH, bb + 4 * NH, nullptr,
            dec_Wout, out + (size_t)c0 * NV, Mb);
    }
}